// Round 3
// baseline (1240.818 us; speedup 1.0000x reference)
//
#include <hip/hip_runtime.h>
#include <hip/hip_bf16.h>
#include <math.h>

#define IN_DIM 512
#define OUT_DIM 256
#define BN_EPS 1e-5f

typedef __attribute__((ext_vector_type(8))) short bf16x8;
typedef __attribute__((ext_vector_type(4))) float f32x4;

// ---------------------------------------------------------------------------
// fp32 -> bf16 hi/lo split (round-to-nearest-even).  a ~= hi + lo, |err| ~ 2^-17|a|
// ---------------------------------------------------------------------------
__device__ __forceinline__ void bf16_split(float f, unsigned short& h, unsigned short& l) {
    unsigned int u  = __float_as_uint(f);
    unsigned int hr = (u + 0x7fffu + ((u >> 16) & 1u)) >> 16;
    h = (unsigned short)hr;
    float hf = __uint_as_float(hr << 16);
    float lo = f - hf;                      // exact (needs <= 24 mantissa bits)
    unsigned int ul = __float_as_uint(lo);
    unsigned int lr = (ul + 0x7fffu + ((ul >> 16) & 1u)) >> 16;
    l = (unsigned short)lr;
}

// ---------------------------------------------------------------------------
// Pre-pass: W [512][256] fp32 -> transposed split Wt_hi/Wt_lo [256][512] bf16
// ---------------------------------------------------------------------------
__global__ void wsplit_kernel(const float* __restrict__ W,
                              unsigned short* __restrict__ Wth,
                              unsigned short* __restrict__ Wtl) {
    int idx = blockIdx.x * 256 + threadIdx.x;
    if (idx >= IN_DIM * OUT_DIM) return;
    int k = idx >> 8;      // /256
    int c = idx & 255;
    unsigned short h, l;
    bf16_split(W[idx], h, l);
    Wth[(size_t)c * IN_DIM + k] = h;
    Wtl[(size_t)c * IN_DIM + k] = l;
}

// ---------------------------------------------------------------------------
// GEMM: support[M][256] = x[M][512] @ W + b   via bf16-split 3-term MFMA
// block = 256 thr (4 waves), tile 64 rows x 256 cols, BK=32
// LDS: 2*(64*40 + 256*40)*2B = 50 KiB -> 3 blocks/CU
// ---------------------------------------------------------------------------
__global__ __launch_bounds__(256)
void gemm_split_kernel(const float* __restrict__ x,
                       const unsigned short* __restrict__ Wth,
                       const unsigned short* __restrict__ Wtl,
                       const float* __restrict__ bias,
                       float* __restrict__ support, int M) {
    __shared__ unsigned short Ah[64][40];
    __shared__ unsigned short Al[64][40];
    __shared__ unsigned short Bh[256][40];
    __shared__ unsigned short Bl[256][40];

    const int tid  = threadIdx.x;
    const int lane = tid & 63;
    const int wv   = tid >> 6;
    const int r0   = blockIdx.x * 64;
    const int l15  = lane & 15;
    const int kk8  = (lane >> 4) * 8;

    f32x4 acc[4][4] = {};

    for (int k0 = 0; k0 < IN_DIM; k0 += 32) {
        // ---- stage A tile (64 x 32) fp32 -> hi/lo bf16 in LDS (coalesced:
        //      consecutive lanes read consecutive float4s)
#pragma unroll
        for (int it = 0; it < 2; ++it) {
            int f4  = it * 256 + tid;      // 0..511 float4 units
            int row = f4 >> 3;
            int kk  = (f4 & 7) * 4;
            float4 v = make_float4(0.f, 0.f, 0.f, 0.f);
            if (r0 + row < M)
                v = *(const float4*)(x + (size_t)(r0 + row) * IN_DIM + k0 + kk);
            unsigned short h0, h1, h2, h3, l0, l1, l2, l3;
            bf16_split(v.x, h0, l0); bf16_split(v.y, h1, l1);
            bf16_split(v.z, h2, l2); bf16_split(v.w, h3, l3);
            uint2 hh = make_uint2((unsigned)h0 | ((unsigned)h1 << 16),
                                  (unsigned)h2 | ((unsigned)h3 << 16));
            uint2 ll = make_uint2((unsigned)l0 | ((unsigned)l1 << 16),
                                  (unsigned)l2 | ((unsigned)l3 << 16));
            *(uint2*)&Ah[row][kk] = hh;
            *(uint2*)&Al[row][kk] = ll;
        }
        // ---- stage B tile (256 cols x 32 k) from pre-split Wt (bf16, 16B coalesced)
#pragma unroll
        for (int it = 0; it < 4; ++it) {
            int u   = tid + it * 256;      // 0..1023 units of 8 bf16
            int col = u >> 2;
            int kk  = (u & 3) * 8;
            *(float4*)&Bh[col][kk] = *(const float4*)(Wth + (size_t)col * IN_DIM + k0 + kk);
            *(float4*)&Bl[col][kk] = *(const float4*)(Wtl + (size_t)col * IN_DIM + k0 + kk);
        }
        __syncthreads();

        bf16x8 ah[4], al[4], bh[4], bl[4];
#pragma unroll
        for (int rf = 0; rf < 4; ++rf) {
            ah[rf] = *(const bf16x8*)&Ah[rf * 16 + l15][kk8];
            al[rf] = *(const bf16x8*)&Al[rf * 16 + l15][kk8];
        }
#pragma unroll
        for (int cf = 0; cf < 4; ++cf) {
            int c = wv * 64 + cf * 16 + l15;
            bh[cf] = *(const bf16x8*)&Bh[c][kk8];
            bl[cf] = *(const bf16x8*)&Bl[c][kk8];
        }
#pragma unroll
        for (int rf = 0; rf < 4; ++rf)
#pragma unroll
            for (int cf = 0; cf < 4; ++cf) {
                acc[rf][cf] = __builtin_amdgcn_mfma_f32_16x16x32_bf16(ah[rf], bh[cf], acc[rf][cf], 0, 0, 0);
                acc[rf][cf] = __builtin_amdgcn_mfma_f32_16x16x32_bf16(ah[rf], bl[cf], acc[rf][cf], 0, 0, 0);
                acc[rf][cf] = __builtin_amdgcn_mfma_f32_16x16x32_bf16(al[rf], bh[cf], acc[rf][cf], 0, 0, 0);
            }
        __syncthreads();
    }

    // epilogue: C/D layout col=lane&15, row=4*(lane>>4)+i  [m89-verified]
    const int rbase = (lane >> 4) * 4;
#pragma unroll
    for (int rf = 0; rf < 4; ++rf)
#pragma unroll
        for (int cf = 0; cf < 4; ++cf) {
            int col    = wv * 64 + cf * 16 + l15;
            float bcol = bias[col];
#pragma unroll
            for (int i = 0; i < 4; ++i) {
                int row = r0 + rf * 16 + rbase + i;
                if (row < M)
                    support[(size_t)row * OUT_DIM + col] = acc[rf][cf][i] + bcol;
            }
        }
}

// ---------------------------------------------------------------------------
// CSR build: histogram -> exclusive scan -> scatter
// ---------------------------------------------------------------------------
__global__ void hist_kernel(const int* __restrict__ edge_row, int* __restrict__ cnt, int E) {
    int e = blockIdx.x * 256 + threadIdx.x;
    if (e < E) atomicAdd(&cnt[edge_row[e]], 1);
}

__global__ void scan_a_kernel(const int* __restrict__ cnt, int* __restrict__ rs,
                              int* __restrict__ bsums, int N) {
    __shared__ int s[1024];
    int i = blockIdx.x * 1024 + threadIdx.x;
    int v = (i < N) ? cnt[i] : 0;
    s[threadIdx.x] = v;
    __syncthreads();
    for (int off = 1; off < 1024; off <<= 1) {
        int u = (threadIdx.x >= (unsigned)off) ? s[threadIdx.x - off] : 0;
        __syncthreads();
        s[threadIdx.x] += u;
        __syncthreads();
    }
    if (i < N) rs[i] = s[threadIdx.x] - v;            // exclusive within block
    if (threadIdx.x == 1023) bsums[blockIdx.x] = s[1023];
}

__global__ void scan_b_kernel(int* __restrict__ bsums, int nb) {
    __shared__ int s[256];
    int t = threadIdx.x;
    int v = (t < nb) ? bsums[t] : 0;
    s[t] = v;
    __syncthreads();
    for (int off = 1; off < 256; off <<= 1) {
        int u = (t >= off) ? s[t - off] : 0;
        __syncthreads();
        s[t] += u;
        __syncthreads();
    }
    if (t < nb) bsums[t] = s[t] - v;                  // exclusive
}

__global__ void scan_c_kernel(int* __restrict__ rs, const int* __restrict__ bsums,
                              int N, int E) {
    int i = blockIdx.x * 1024 + threadIdx.x;
    if (i < N) rs[i] += bsums[blockIdx.x];
    if (i == 0) rs[N] = E;
}

__global__ void scatter_kernel(const int* __restrict__ er, const int* __restrict__ ec,
                               const float* __restrict__ ev,
                               const int* __restrict__ row_start, int* __restrict__ cursor,
                               int* __restrict__ csr_col, float* __restrict__ csr_val, int E) {
    int e = blockIdx.x * 256 + threadIdx.x;
    if (e >= E) return;
    int r = er[e];
    int p = row_start[r] + atomicAdd(&cursor[r], 1);
    csr_col[p] = ec[e];
    csr_val[p] = ev[e];
}

// ---------------------------------------------------------------------------
// SpMM + BatchNorm(eval) + exact GELU.  One wave per destination row,
// lane owns 4 consecutive dims (float4).  No fp32 atomics.
// 4-deep unroll: 4 independent 16B gathers in flight per lane.
// ---------------------------------------------------------------------------
__global__ __launch_bounds__(256)
void spmm_bn_gelu_kernel(const float* __restrict__ support,
                         const int* __restrict__ csr_col,
                         const float* __restrict__ csr_val,
                         const int* __restrict__ row_start,
                         const float* __restrict__ gamma,
                         const float* __restrict__ beta,
                         const float* __restrict__ mean,
                         const float* __restrict__ var,
                         float* __restrict__ out, int N) {
    int r = blockIdx.x * 4 + (threadIdx.x >> 6);
    if (r >= N) return;
    int lane = threadIdx.x & 63;
    int d = lane * 4;
    const float* supd = support + d;       // hoist per-lane dim offset

    int e  = row_start[r];
    int e1 = row_start[r + 1];

    f32x4 acc0 = {0.f, 0.f, 0.f, 0.f};
    f32x4 acc1 = {0.f, 0.f, 0.f, 0.f};
    f32x4 acc2 = {0.f, 0.f, 0.f, 0.f};
    f32x4 acc3 = {0.f, 0.f, 0.f, 0.f};

    for (; e + 4 <= e1; e += 4) {
        int   s0 = csr_col[e];     float v0 = csr_val[e];
        int   s1 = csr_col[e + 1]; float v1 = csr_val[e + 1];
        int   s2 = csr_col[e + 2]; float v2 = csr_val[e + 2];
        int   s3 = csr_col[e + 3]; float v3 = csr_val[e + 3];
        const f32x4 t0 = *(const f32x4*)(supd + (size_t)s0 * OUT_DIM);
        const f32x4 t1 = *(const f32x4*)(supd + (size_t)s1 * OUT_DIM);
        const f32x4 t2 = *(const f32x4*)(supd + (size_t)s2 * OUT_DIM);
        const f32x4 t3 = *(const f32x4*)(supd + (size_t)s3 * OUT_DIM);
        acc0 += v0 * t0;
        acc1 += v1 * t1;
        acc2 += v2 * t2;
        acc3 += v3 * t3;
    }
    for (; e < e1; ++e) {
        int   s0 = csr_col[e];
        float v0 = csr_val[e];
        const f32x4 t0 = *(const f32x4*)(supd + (size_t)s0 * OUT_DIM);
        acc0 += v0 * t0;
    }
    f32x4 a = (acc0 + acc1) + (acc2 + acc3);

    float4 mn = *(const float4*)(mean + d);
    float4 vr = *(const float4*)(var + d);
    float4 gm = *(const float4*)(gamma + d);
    float4 bt = *(const float4*)(beta + d);

    auto bng = [](float a, float m, float v, float g, float b) -> float {
        float ve = v + BN_EPS;
        float iv = rsqrtf(ve);
        iv = iv * (1.5f - 0.5f * ve * iv * iv);       // one NR step -> ~fp32 exact
        float xx = (a - m) * iv * g + b;
        return 0.5f * xx * (1.0f + erff(xx * 0.70710678118654752f));
    };

    float4 o;
    o.x = bng(a[0], mn.x, vr.x, gm.x, bt.x);
    o.y = bng(a[1], mn.y, vr.y, gm.y, bt.y);
    o.z = bng(a[2], mn.z, vr.z, gm.z, bt.z);
    o.w = bng(a[3], mn.w, vr.w, gm.w, bt.w);
    *(float4*)(out + (size_t)r * OUT_DIM + d) = o;
}

// ---------------------------------------------------------------------------
extern "C" void kernel_launch(void* const* d_in, const int* in_sizes, int n_in,
                              void* d_out, int out_size, void* d_ws, size_t ws_size,
                              hipStream_t stream) {
    const float* x        = (const float*)d_in[0];
    const int*   edge_row = (const int*)d_in[1];
    const int*   edge_col = (const int*)d_in[2];
    const float* edge_val = (const float*)d_in[3];
    const float* W        = (const float*)d_in[4];
    const float* b        = (const float*)d_in[5];
    const float* gamma    = (const float*)d_in[6];
    const float* beta     = (const float*)d_in[7];
    const float* rmean    = (const float*)d_in[8];
    const float* rvar     = (const float*)d_in[9];
    float* out = (float*)d_out;

    const int N = in_sizes[0] / IN_DIM;
    const int E = in_sizes[1];

    char* p = (char*)d_ws;
    auto alloc = [&](size_t bytes) -> char* {
        char* q = p;
        p += (bytes + 255) & ~(size_t)255;
        return q;
    };
    float*          support  = (float*)alloc((size_t)N * OUT_DIM * 4);
    unsigned short* Wth      = (unsigned short*)alloc((size_t)IN_DIM * OUT_DIM * 2);
    unsigned short* Wtl      = (unsigned short*)alloc((size_t)IN_DIM * OUT_DIM * 2);
    int*            csr_col  = (int*)alloc((size_t)E * 4);
    float*          csr_val  = (float*)alloc((size_t)E * 4);
    int*            row_start= (int*)alloc((size_t)(N + 1) * 4);
    int*            cnt      = (int*)alloc((size_t)N * 4);
    int*            cursor   = (int*)alloc((size_t)N * 4);
    int*            bsums    = (int*)alloc(1024);

    hipMemsetAsync(cnt, 0, (size_t)N * 4, stream);
    hipMemsetAsync(cursor, 0, (size_t)N * 4, stream);

    wsplit_kernel<<<(IN_DIM * OUT_DIM + 255) / 256, 256, 0, stream>>>(W, Wth, Wtl);
    hist_kernel<<<(E + 255) / 256, 256, 0, stream>>>(edge_row, cnt, E);

    int nb = (N + 1023) / 1024;
    scan_a_kernel<<<nb, 1024, 0, stream>>>(cnt, row_start, bsums, N);
    scan_b_kernel<<<1, 256, 0, stream>>>(bsums, nb);
    scan_c_kernel<<<nb, 1024, 0, stream>>>(row_start, bsums, N, E);

    scatter_kernel<<<(E + 255) / 256, 256, 0, stream>>>(edge_row, edge_col, edge_val,
                                                        row_start, cursor, csr_col, csr_val, E);

    gemm_split_kernel<<<(N + 63) / 64, 256, 0, stream>>>(x, Wth, Wtl, b, support, N);

    spmm_bn_gelu_kernel<<<(N + 3) / 4, 256, 0, stream>>>(support, csr_col, csr_val, row_start,
                                                         gamma, beta, rmean, rvar, out, N);
}

// Round 4
// 1190.470 us; speedup vs baseline: 1.0423x; 1.0423x over previous
//
#include <hip/hip_runtime.h>
#include <hip/hip_bf16.h>
#include <math.h>

#define IN_DIM 512
#define OUT_DIM 256
#define BN_EPS 1e-5f

typedef __attribute__((ext_vector_type(8))) short bf16x8;
typedef __attribute__((ext_vector_type(4))) float f32x4;
typedef __attribute__((ext_vector_type(2))) float f32x2;

// ---------------------------------------------------------------------------
// fp32 -> bf16 hi/lo split (round-to-nearest-even).  a ~= hi + lo, |err| ~ 2^-17|a|
// ---------------------------------------------------------------------------
__device__ __forceinline__ void bf16_split(float f, unsigned short& h, unsigned short& l) {
    unsigned int u  = __float_as_uint(f);
    unsigned int hr = (u + 0x7fffu + ((u >> 16) & 1u)) >> 16;
    h = (unsigned short)hr;
    float hf = __uint_as_float(hr << 16);
    float lo = f - hf;                      // exact (needs <= 24 mantissa bits)
    unsigned int ul = __float_as_uint(lo);
    unsigned int lr = (ul + 0x7fffu + ((ul >> 16) & 1u)) >> 16;
    l = (unsigned short)lr;
}

// ---------------------------------------------------------------------------
// Pre-pass: W [512][256] fp32 -> transposed split Wt_hi/Wt_lo [256][512] bf16
// ---------------------------------------------------------------------------
__global__ void wsplit_kernel(const float* __restrict__ W,
                              unsigned short* __restrict__ Wth,
                              unsigned short* __restrict__ Wtl) {
    int idx = blockIdx.x * 256 + threadIdx.x;
    if (idx >= IN_DIM * OUT_DIM) return;
    int k = idx >> 8;      // /256
    int c = idx & 255;
    unsigned short h, l;
    bf16_split(W[idx], h, l);
    Wth[(size_t)c * IN_DIM + k] = h;
    Wtl[(size_t)c * IN_DIM + k] = l;
}

// ---------------------------------------------------------------------------
// GEMM: support[M][256] = x[M][512] @ W + b   via bf16-split 3-term MFMA
// (unchanged from passing R3 version -- will be profiled this round)
// ---------------------------------------------------------------------------
__global__ __launch_bounds__(256)
void gemm_split_kernel(const float* __restrict__ x,
                       const unsigned short* __restrict__ Wth,
                       const unsigned short* __restrict__ Wtl,
                       const float* __restrict__ bias,
                       float* __restrict__ support, int M) {
    __shared__ unsigned short Ah[64][40];
    __shared__ unsigned short Al[64][40];
    __shared__ unsigned short Bh[256][40];
    __shared__ unsigned short Bl[256][40];

    const int tid  = threadIdx.x;
    const int lane = tid & 63;
    const int wv   = tid >> 6;
    const int r0   = blockIdx.x * 64;
    const int l15  = lane & 15;
    const int kk8  = (lane >> 4) * 8;

    f32x4 acc[4][4] = {};

    for (int k0 = 0; k0 < IN_DIM; k0 += 32) {
#pragma unroll
        for (int it = 0; it < 2; ++it) {
            int f4  = it * 256 + tid;
            int row = f4 >> 3;
            int kk  = (f4 & 7) * 4;
            float4 v = make_float4(0.f, 0.f, 0.f, 0.f);
            if (r0 + row < M)
                v = *(const float4*)(x + (size_t)(r0 + row) * IN_DIM + k0 + kk);
            unsigned short h0, h1, h2, h3, l0, l1, l2, l3;
            bf16_split(v.x, h0, l0); bf16_split(v.y, h1, l1);
            bf16_split(v.z, h2, l2); bf16_split(v.w, h3, l3);
            uint2 hh = make_uint2((unsigned)h0 | ((unsigned)h1 << 16),
                                  (unsigned)h2 | ((unsigned)h3 << 16));
            uint2 ll = make_uint2((unsigned)l0 | ((unsigned)l1 << 16),
                                  (unsigned)l2 | ((unsigned)l3 << 16));
            *(uint2*)&Ah[row][kk] = hh;
            *(uint2*)&Al[row][kk] = ll;
        }
#pragma unroll
        for (int it = 0; it < 4; ++it) {
            int u   = tid + it * 256;
            int col = u >> 2;
            int kk  = (u & 3) * 8;
            *(float4*)&Bh[col][kk] = *(const float4*)(Wth + (size_t)col * IN_DIM + k0 + kk);
            *(float4*)&Bl[col][kk] = *(const float4*)(Wtl + (size_t)col * IN_DIM + k0 + kk);
        }
        __syncthreads();

        bf16x8 ah[4], al[4], bh[4], bl[4];
#pragma unroll
        for (int rf = 0; rf < 4; ++rf) {
            ah[rf] = *(const bf16x8*)&Ah[rf * 16 + l15][kk8];
            al[rf] = *(const bf16x8*)&Al[rf * 16 + l15][kk8];
        }
#pragma unroll
        for (int cf = 0; cf < 4; ++cf) {
            int c = wv * 64 + cf * 16 + l15;
            bh[cf] = *(const bf16x8*)&Bh[c][kk8];
            bl[cf] = *(const bf16x8*)&Bl[c][kk8];
        }
#pragma unroll
        for (int rf = 0; rf < 4; ++rf)
#pragma unroll
            for (int cf = 0; cf < 4; ++cf) {
                acc[rf][cf] = __builtin_amdgcn_mfma_f32_16x16x32_bf16(ah[rf], bh[cf], acc[rf][cf], 0, 0, 0);
                acc[rf][cf] = __builtin_amdgcn_mfma_f32_16x16x32_bf16(ah[rf], bl[cf], acc[rf][cf], 0, 0, 0);
                acc[rf][cf] = __builtin_amdgcn_mfma_f32_16x16x32_bf16(al[rf], bh[cf], acc[rf][cf], 0, 0, 0);
            }
        __syncthreads();
    }

    const int rbase = (lane >> 4) * 4;
#pragma unroll
    for (int rf = 0; rf < 4; ++rf)
#pragma unroll
        for (int cf = 0; cf < 4; ++cf) {
            int col    = wv * 64 + cf * 16 + l15;
            float bcol = bias[col];
#pragma unroll
            for (int i = 0; i < 4; ++i) {
                int row = r0 + rf * 16 + rbase + i;
                if (row < M)
                    support[(size_t)row * OUT_DIM + col] = acc[rf][cf][i] + bcol;
            }
        }
}

// ---------------------------------------------------------------------------
// CSR build: histogram -> exclusive scan -> scatter (packed 8B col|val)
// ---------------------------------------------------------------------------
__global__ void hist_kernel(const int* __restrict__ edge_row, int* __restrict__ cnt, int E) {
    int e = blockIdx.x * 256 + threadIdx.x;
    if (e < E) atomicAdd(&cnt[edge_row[e]], 1);
}

__global__ void scan_a_kernel(const int* __restrict__ cnt, int* __restrict__ rs,
                              int* __restrict__ bsums, int N) {
    __shared__ int s[1024];
    int i = blockIdx.x * 1024 + threadIdx.x;
    int v = (i < N) ? cnt[i] : 0;
    s[threadIdx.x] = v;
    __syncthreads();
    for (int off = 1; off < 1024; off <<= 1) {
        int u = (threadIdx.x >= (unsigned)off) ? s[threadIdx.x - off] : 0;
        __syncthreads();
        s[threadIdx.x] += u;
        __syncthreads();
    }
    if (i < N) rs[i] = s[threadIdx.x] - v;            // exclusive within block
    if (threadIdx.x == 1023) bsums[blockIdx.x] = s[1023];
}

__global__ void scan_b_kernel(int* __restrict__ bsums, int nb) {
    __shared__ int s[256];
    int t = threadIdx.x;
    int v = (t < nb) ? bsums[t] : 0;
    s[t] = v;
    __syncthreads();
    for (int off = 1; off < 256; off <<= 1) {
        int u = (t >= off) ? s[t - off] : 0;
        __syncthreads();
        s[t] += u;
        __syncthreads();
    }
    if (t < nb) bsums[t] = s[t] - v;                  // exclusive
}

__global__ void scan_c_kernel(int* __restrict__ rs, const int* __restrict__ bsums,
                              int N, int E) {
    int i = blockIdx.x * 1024 + threadIdx.x;
    if (i < N) rs[i] += bsums[blockIdx.x];
    if (i == 0) rs[N] = E;
}

__global__ void scatter_kernel(const int* __restrict__ er, const int* __restrict__ ec,
                               const float* __restrict__ ev,
                               const int* __restrict__ row_start, int* __restrict__ cursor,
                               unsigned long long* __restrict__ csr, int E) {
    int e = blockIdx.x * 256 + threadIdx.x;
    if (e >= E) return;
    int r = er[e];
    int p = row_start[r] + atomicAdd(&cursor[r], 1);
    csr[p] = (unsigned long long)(unsigned)ec[e] |
             ((unsigned long long)__float_as_uint(ev[e]) << 32);
}

// ---------------------------------------------------------------------------
// SpMM + BatchNorm(eval) + exact GELU.
// 2 waves per destination row (each wave owns 128 dims, f32x2 per lane).
// 4-deep double-buffered gather pipeline; sched_barrier pins loads before FMAs.
// NT stores for out, NT loads for CSR -> keep support L3-resident.
// ---------------------------------------------------------------------------
__global__ __launch_bounds__(256)
void spmm_bn_gelu_kernel(const float* __restrict__ support,
                         const unsigned long long* __restrict__ csr,
                         const int* __restrict__ row_start,
                         const float* __restrict__ gamma,
                         const float* __restrict__ beta,
                         const float* __restrict__ mean,
                         const float* __restrict__ var,
                         float* __restrict__ out, int N) {
    const int wid  = threadIdx.x >> 6;                 // 0..3
    const int r    = blockIdx.x * 2 + (wid >> 1);
    if (r >= N) return;
    const int lane = threadIdx.x & 63;
    const int d    = (wid & 1) * 128 + lane * 2;       // this wave's 2 dims
    const float* supd = support + d;

    int e        = row_start[r];
    const int e1 = row_start[r + 1];

    f32x2 acc0 = {0.f, 0.f}, acc1 = {0.f, 0.f}, acc2 = {0.f, 0.f}, acc3 = {0.f, 0.f};

    if (e + 4 <= e1) {
        unsigned long long q0 = __builtin_nontemporal_load(csr + e);
        unsigned long long q1 = __builtin_nontemporal_load(csr + e + 1);
        unsigned long long q2 = __builtin_nontemporal_load(csr + e + 2);
        unsigned long long q3 = __builtin_nontemporal_load(csr + e + 3);
        f32x2 t0 = *(const f32x2*)(supd + ((size_t)(unsigned)q0) * OUT_DIM);
        f32x2 t1 = *(const f32x2*)(supd + ((size_t)(unsigned)q1) * OUT_DIM);
        f32x2 t2 = *(const f32x2*)(supd + ((size_t)(unsigned)q2) * OUT_DIM);
        f32x2 t3 = *(const f32x2*)(supd + ((size_t)(unsigned)q3) * OUT_DIM);
        float v0 = __uint_as_float((unsigned)(q0 >> 32));
        float v1 = __uint_as_float((unsigned)(q1 >> 32));
        float v2 = __uint_as_float((unsigned)(q2 >> 32));
        float v3 = __uint_as_float((unsigned)(q3 >> 32));
        e += 4;
        for (; e + 4 <= e1; e += 4) {
            unsigned long long p0 = __builtin_nontemporal_load(csr + e);
            unsigned long long p1 = __builtin_nontemporal_load(csr + e + 1);
            unsigned long long p2 = __builtin_nontemporal_load(csr + e + 2);
            unsigned long long p3 = __builtin_nontemporal_load(csr + e + 3);
            f32x2 u0 = *(const f32x2*)(supd + ((size_t)(unsigned)p0) * OUT_DIM);
            f32x2 u1 = *(const f32x2*)(supd + ((size_t)(unsigned)p1) * OUT_DIM);
            f32x2 u2 = *(const f32x2*)(supd + ((size_t)(unsigned)p2) * OUT_DIM);
            f32x2 u3 = *(const f32x2*)(supd + ((size_t)(unsigned)p3) * OUT_DIM);
            float w0 = __uint_as_float((unsigned)(p0 >> 32));
            float w1 = __uint_as_float((unsigned)(p1 >> 32));
            float w2 = __uint_as_float((unsigned)(p2 >> 32));
            float w3 = __uint_as_float((unsigned)(p3 >> 32));
            __builtin_amdgcn_sched_barrier(0);   // loads above stay above FMAs
            acc0 += v0 * t0; acc1 += v1 * t1; acc2 += v2 * t2; acc3 += v3 * t3;
            t0 = u0; t1 = u1; t2 = u2; t3 = u3;
            v0 = w0; v1 = w1; v2 = w2; v3 = w3;
        }
        acc0 += v0 * t0; acc1 += v1 * t1; acc2 += v2 * t2; acc3 += v3 * t3;
    }
    for (; e < e1; ++e) {
        unsigned long long q = __builtin_nontemporal_load(csr + e);
        f32x2 t = *(const f32x2*)(supd + ((size_t)(unsigned)q) * OUT_DIM);
        float v = __uint_as_float((unsigned)(q >> 32));
        acc0 += v * t;
    }
    f32x2 a = (acc0 + acc1) + (acc2 + acc3);

    f32x2 mn = *(const f32x2*)(mean + d);
    f32x2 vr = *(const f32x2*)(var + d);
    f32x2 gm = *(const f32x2*)(gamma + d);
    f32x2 bt = *(const f32x2*)(beta + d);

    auto bng = [](float a, float m, float v, float g, float b) -> float {
        float ve = v + BN_EPS;
        float iv = rsqrtf(ve);
        iv = iv * (1.5f - 0.5f * ve * iv * iv);       // one NR step -> ~fp32 exact
        float xx = (a - m) * iv * g + b;
        return 0.5f * xx * (1.0f + erff(xx * 0.70710678118654752f));
    };

    f32x2 o;
    o[0] = bng(a[0], mn[0], vr[0], gm[0], bt[0]);
    o[1] = bng(a[1], mn[1], vr[1], gm[1], bt[1]);
    __builtin_nontemporal_store(o, (f32x2*)(out + (size_t)r * OUT_DIM + d));
}

// ---------------------------------------------------------------------------
extern "C" void kernel_launch(void* const* d_in, const int* in_sizes, int n_in,
                              void* d_out, int out_size, void* d_ws, size_t ws_size,
                              hipStream_t stream) {
    const float* x        = (const float*)d_in[0];
    const int*   edge_row = (const int*)d_in[1];
    const int*   edge_col = (const int*)d_in[2];
    const float* edge_val = (const float*)d_in[3];
    const float* W        = (const float*)d_in[4];
    const float* b        = (const float*)d_in[5];
    const float* gamma    = (const float*)d_in[6];
    const float* beta     = (const float*)d_in[7];
    const float* rmean    = (const float*)d_in[8];
    const float* rvar     = (const float*)d_in[9];
    float* out = (float*)d_out;

    const int N = in_sizes[0] / IN_DIM;
    const int E = in_sizes[1];

    char* p = (char*)d_ws;
    auto alloc = [&](size_t bytes) -> char* {
        char* q = p;
        p += (bytes + 255) & ~(size_t)255;
        return q;
    };
    float*              support   = (float*)alloc((size_t)N * OUT_DIM * 4);
    unsigned short*     Wth       = (unsigned short*)alloc((size_t)IN_DIM * OUT_DIM * 2);
    unsigned short*     Wtl       = (unsigned short*)alloc((size_t)IN_DIM * OUT_DIM * 2);
    unsigned long long* csr       = (unsigned long long*)alloc((size_t)E * 8);
    int*                row_start = (int*)alloc((size_t)(N + 1) * 4);
    int*                cnt       = (int*)alloc((size_t)N * 4);
    int*                cursor    = (int*)alloc((size_t)N * 4);
    int*                bsums     = (int*)alloc(1024);

    hipMemsetAsync(cnt, 0, (size_t)N * 4, stream);
    hipMemsetAsync(cursor, 0, (size_t)N * 4, stream);

    wsplit_kernel<<<(IN_DIM * OUT_DIM + 255) / 256, 256, 0, stream>>>(W, Wth, Wtl);
    hist_kernel<<<(E + 255) / 256, 256, 0, stream>>>(edge_row, cnt, E);

    int nb = (N + 1023) / 1024;
    scan_a_kernel<<<nb, 1024, 0, stream>>>(cnt, row_start, bsums, N);
    scan_b_kernel<<<1, 256, 0, stream>>>(bsums, nb);
    scan_c_kernel<<<nb, 1024, 0, stream>>>(row_start, bsums, N, E);

    scatter_kernel<<<(E + 255) / 256, 256, 0, stream>>>(edge_row, edge_col, edge_val,
                                                        row_start, cursor, csr, E);

    gemm_split_kernel<<<(N + 63) / 64, 256, 0, stream>>>(x, Wth, Wtl, b, support, N);

    spmm_bn_gelu_kernel<<<(N + 1) / 2, 256, 0, stream>>>(support, csr, row_start,
                                                         gamma, beta, rmean, rvar, out, N);
}